// Round 2
// baseline (546.863 us; speedup 1.0000x reference)
//
#include <hip/hip_runtime.h>

// DeltaModulationEncoder: x (16, 256, 8192) f32 -> spikes {-1,0,1} f32.
// Speculative time-segmentation + iterative parallel heal + sequential
// guarantee pass. Bit-exact vs the f32 reference semantics.

constexpr float TH   = 0.1f;
constexpr int   T    = 8192;
constexpr int   NCH  = 16 * 256;   // 4096 channels
constexpr int   SEG  = 512;        // segment length
constexpr int   NSEG = T / SEG;    // 16 segments/channel
constexpr int   W    = 128;        // warm-up lookback
constexpr int   PF   = 4;          // prefetch depth (chunks of 16 floats)

// err = x - recon; net = (err>th)-(err<-th); recon += net*th; spike = net.
// nth in {-0.1f,0,+0.1f} exact; single f32 add matches reference; nth*10.0f
// rounds exactly to {-1,0,1}.
__device__ __forceinline__ void dm_step(float xv, float& recon, float& spike) {
    float err = xv - recon;
    float nth = 0.0f;
    nth = (err > TH)  ?  TH : nth;
    nth = (err < -TH) ? -TH : nth;
    recon += nth;
    spike = nth * 10.0f;
}

__device__ __forceinline__ void proc4(const float4 c, float& recon, float4& s) {
    dm_step(c.x, recon, s.x);
    dm_step(c.y, recon, s.y);
    dm_step(c.z, recon, s.z);
    dm_step(c.w, recon, s.w);
}

// NCHUNK chunks of 16 floats, PF-deep software-pipelined loads (256 B/lane in
// flight). Fully unrolled so buf[] indices are compile-time (registers, not
// scratch).
template<bool STORE, int NCHUNK>
__device__ __forceinline__ float run_span(const float4* __restrict__ pin,
                                          float4* __restrict__ pout,
                                          float recon) {
    float4 buf[PF][4];
#pragma unroll
    for (int i = 0; i < PF; ++i) {
        if (i < NCHUNK) {
#pragma unroll
            for (int j = 0; j < 4; ++j) buf[i][j] = pin[4 * i + j];
        }
    }
#pragma unroll
    for (int k = 0; k < NCHUNK; ++k) {
        constexpr int M = PF;
        const int slot = k % M;  // compile-time under full unroll
        float4 c0 = buf[slot][0], c1 = buf[slot][1];
        float4 c2 = buf[slot][2], c3 = buf[slot][3];
        if (k + PF < NCHUNK) {
            const float4* p = pin + 4 * (k + PF);
#pragma unroll
            for (int j = 0; j < 4; ++j) buf[slot][j] = p[j];
        }
        float4 s0, s1, s2, s3;
        proc4(c0, recon, s0);
        proc4(c1, recon, s1);
        proc4(c2, recon, s2);
        proc4(c3, recon, s3);
        if (STORE) {
            float4* q = pout + 4 * k;
            q[0] = s0; q[1] = s1; q[2] = s2; q[3] = s3;
        }
    }
    return recon;
}

// Round 0: one thread per (channel, segment). s==0 starts exactly at 0;
// s>0 warms up over previous W samples from guess 0, records the entry state
// actually used and the resulting end state.
__global__ __launch_bounds__(256) void dm_round0(const float* __restrict__ x,
                                                 float* __restrict__ out,
                                                 float* __restrict__ end_st,
                                                 float* __restrict__ entry_st) {
    int tid = blockIdx.x * 256 + threadIdx.x;   // tid = ch*NSEG + s
    int s   = tid & (NSEG - 1);
    int ch  = tid >> 4;                          // log2(NSEG) == 4
    const float* px = x   + (size_t)ch * T + (size_t)s * SEG;
    float*       po = out + (size_t)ch * T + (size_t)s * SEG;

    float recon = 0.0f;
    if (s != 0) {
        recon = run_span<false, W / 16>((const float4*)(px - W), nullptr, 0.0f);
    }
    entry_st[tid] = recon;
    recon = run_span<true, SEG / 16>((const float4*)px, (float4*)po, recon);
    end_st[tid] = recon;
}

// Heal pass: parallel over all (ch, s>0). If this segment's recorded entry
// no longer matches the predecessor's (possibly updated) end state, recompute
// from it. Kernel boundaries between passes give cross-XCD visibility; the
// exactness frontier advances >=1 segment per pass, and wrong-entry segments
// usually coalesce to the exact end within 512 steps, so failures decay
// geometrically.
__global__ __launch_bounds__(256) void dm_heal(const float* __restrict__ x,
                                               float* __restrict__ out,
                                               float* __restrict__ end_st,
                                               float* __restrict__ entry_st) {
    int tid = blockIdx.x * 256 + threadIdx.x;
    int s   = tid & (NSEG - 1);
    if (s == 0) return;
    int ch  = tid >> 4;
    float e = end_st[tid - 1];
    if (entry_st[tid] == e) return;
    entry_st[tid] = e;
    const float4* pin  = (const float4*)(x   + (size_t)ch * T + (size_t)s * SEG);
    float4*       pout = (float4*)      (out + (size_t)ch * T + (size_t)s * SEG);
    end_st[tid] = run_span<true, SEG / 16>(pin, pout, e);
}

// Guarantee pass: one thread per channel walks the chain with the exactly-
// known state. After the heal passes this is expected to skip everything
// (pure array walk); exact by induction regardless.
__global__ __launch_bounds__(256) void dm_fixup(const float* __restrict__ x,
                                                float* __restrict__ out,
                                                float* __restrict__ end_st,
                                                const float* __restrict__ entry_st) {
    int ch = blockIdx.x * 256 + threadIdx.x;
    if (ch >= NCH) return;
    float v = end_st[(size_t)ch * NSEG];  // segment 0 always exact
    for (int s = 1; s < NSEG; ++s) {
        int idx = ch * NSEG + s;
        if (entry_st[idx] == v) {
            v = end_st[idx];
        } else {
            const float4* pin  = (const float4*)(x   + (size_t)ch * T + (size_t)s * SEG);
            float4*       pout = (float4*)      (out + (size_t)ch * T + (size_t)s * SEG);
            v = run_span<true, SEG / 16>(pin, pout, v);
            end_st[idx] = v;
        }
    }
}

// Fallback if workspace is too small: plain sequential scan per channel.
__global__ __launch_bounds__(256) void dm_sequential(const float* __restrict__ x,
                                                     float* __restrict__ out) {
    int ch = blockIdx.x * 256 + threadIdx.x;
    if (ch >= NCH) return;
    const float4* pin  = (const float4*)(x   + (size_t)ch * T);
    float4*       pout = (float4*)      (out + (size_t)ch * T);
    run_span<true, T / 16>(pin, pout, 0.0f);
}

extern "C" void kernel_launch(void* const* d_in, const int* in_sizes, int n_in,
                              void* d_out, int out_size, void* d_ws, size_t ws_size,
                              hipStream_t stream) {
    const float* x   = (const float*)d_in[0];
    float*       out = (float*)d_out;

    size_t st_elems = (size_t)NCH * NSEG;           // 65536 floats per array
    if (ws_size < 2 * st_elems * sizeof(float)) {
        dm_sequential<<<NCH / 256, 256, 0, stream>>>(x, out);
        return;
    }
    float* end_st   = (float*)d_ws;
    float* entry_st = end_st + st_elems;

    dm_round0<<<(NCH * NSEG) / 256, 256, 0, stream>>>(x, out, end_st, entry_st);
    dm_heal  <<<(NCH * NSEG) / 256, 256, 0, stream>>>(x, out, end_st, entry_st);
    dm_heal  <<<(NCH * NSEG) / 256, 256, 0, stream>>>(x, out, end_st, entry_st);
    dm_heal  <<<(NCH * NSEG) / 256, 256, 0, stream>>>(x, out, end_st, entry_st);
    dm_fixup <<<NCH / 256, 256, 0, stream>>>(x, out, end_st, entry_st);
}

// Round 3
// 274.493 us; speedup vs baseline: 1.9923x; 1.9923x over previous
//
#include <hip/hip_runtime.h>

// DeltaModulationEncoder: x (16, 256, 8192) f32 -> spikes {-1,0,1} f32.
// Exact monolithic scan: 4096 channels (one lane each), 64 waves.
// The 8192-step recurrence is inherently sequential per channel; this kernel
// is engineered to the chain/issue floor:
//   - x staged global->LDS via __builtin_amdgcn_global_load_lds (coalesced
//     256B DMA per channel-row half; no VGPR roundtrip), double-buffered
//     across 128-step tiles, one s_waitcnt vmcnt(0) per tile.
//   - LDS rows padded to 132 floats: 16B-aligned ds_read_b128, lanes spread
//     over 8 bank-quads (m214-style swizzle effect via pad alone).
//   - spikes stored directly (per-lane dwordx4, fire-and-forget).

constexpr float TH    = 0.1f;
constexpr int   T     = 8192;
constexpr int   TILE  = 128;          // timesteps per staged tile
constexpr int   NTILE = T / TILE;     // 64
constexpr int   ROWF  = 132;          // 128 + 4 pad floats (16B-aligned rows)

typedef __attribute__((address_space(1))) const float gfloat;
typedef __attribute__((address_space(3))) float       lfloat;

// DMA one dword per lane: global (per-lane addr) -> LDS base + 4*lane.
__device__ __forceinline__ void gload_lds4(const float* g, float* l) {
    __builtin_amdgcn_global_load_lds((gfloat*)g, (lfloat*)l, 4, 0, 0);
}

// Bit-exact reference step:
//   err = x - recon; net = (err>th)-(err<-th); recon += net*th; spike = net.
// nth in {0, +0.1f, -0.1f} exact; recon update is the same single f32 add as
// the reference (incl. +0.0f when net==0); nth*10.0f is exactly {-1,0,1}.
// No mul feeds an add, so FMA contraction cannot change rounding.
__device__ __forceinline__ void dm_step(float xv, float& recon, float& spike) {
    float err = xv - recon;
    float nth = 0.0f;
    nth = (err > TH)  ?  TH : nth;
    nth = (err < -TH) ? -TH : nth;
    recon += nth;
    spike = nth * 10.0f;
}

__device__ __forceinline__ void proc4(const float4 c, float& recon, float4& s) {
    dm_step(c.x, recon, s.x);
    dm_step(c.y, recon, s.y);
    dm_step(c.z, recon, s.z);
    dm_step(c.w, recon, s.w);
}

__global__ __launch_bounds__(64) void dm_scan(const float* __restrict__ x,
                                              float* __restrict__ out) {
    __shared__ float xb[2][64][ROWF];
    const int lane   = threadIdx.x;        // 0..63; lane l owns channel chBase+l
    const int chBase = blockIdx.x * 64;

    // Stage tile tt into buffer b: per channel row j, two 256B DMA transfers
    // (64 floats each). LDS dest is wave-uniform; HW scatters lane -> +4*lane,
    // which exactly matches x[ch][t0 + h*64 + lane] -> xb[b][j][h*64 + lane].
    auto stage = [&](int tt, int b) {
        const float* base = x + (size_t)chBase * T + (size_t)tt * TILE + lane;
#pragma unroll 8
        for (int j = 0; j < 64; ++j) {
            const float* g = base + (size_t)j * T;
            gload_lds4(g,      &xb[b][j][0]);
            gload_lds4(g + 64, &xb[b][j][64]);
        }
    };

    stage(0, 0);

    float  recon = 0.0f;
    float* orow  = out + (size_t)(chBase + lane) * T;

    for (int tt = 0; tt < NTILE; ++tt) {
        const int b = tt & 1;
        // Tile tt's DMA complete (also drains our in-flight stores). One wave
        // per block -> no s_barrier needed; "memory" clobber orders the
        // following ds_reads after the wait.
        asm volatile("s_waitcnt vmcnt(0)" ::: "memory");
        if (tt + 1 < NTILE) stage(tt + 1, b ^ 1);  // prefetch next tile (async)

        const float4* r4 = (const float4*)&xb[b][lane][0];
        float4*       po = (float4*)(orow + (size_t)tt * TILE);
#pragma unroll
        for (int k = 0; k < TILE / 16; ++k) {
            float4 c0 = r4[4 * k + 0], c1 = r4[4 * k + 1];
            float4 c2 = r4[4 * k + 2], c3 = r4[4 * k + 3];
            float4 s0, s1, s2, s3;
            proc4(c0, recon, s0);
            proc4(c1, recon, s1);
            proc4(c2, recon, s2);
            proc4(c3, recon, s3);
            po[4 * k + 0] = s0; po[4 * k + 1] = s1;
            po[4 * k + 2] = s2; po[4 * k + 3] = s3;
        }
    }
}

extern "C" void kernel_launch(void* const* d_in, const int* in_sizes, int n_in,
                              void* d_out, int out_size, void* d_ws, size_t ws_size,
                              hipStream_t stream) {
    const float* x   = (const float*)d_in[0];
    float*       out = (float*)d_out;
    // 4096 channels = 64 blocks x 64 threads (1 wave each).
    dm_scan<<<64, 64, 0, stream>>>(x, out);
}

// Round 4
// 244.834 us; speedup vs baseline: 2.2336x; 1.1211x over previous
//
#include <hip/hip_runtime.h>

// DeltaModulationEncoder: x (16, 256, 8192) f32 -> spikes {-1,0,1} f32.
// Exact monolithic scan (recurrence is inherently serial per channel).
// Structure: 256 blocks x 1 wave; 16 channels/block (lanes 0-15 compute,
// all 64 lanes drive DMA). Per 128-step tile:
//   - 8 x 1024B global_load_lds (16B/lane, 2 rows per instr), double-buffered,
//     precomputed 32-bit per-lane voffsets, <=8 outstanding (vmcnt cap 63).
//   - LDS linear [2][16][128] (DMA needs lane-linear dest); bank conflicts
//     killed by XOR swizzle applied on BOTH sides (rule #21): the DMA source
//     fetches chunk (slot ^ (row&7)), the ds_read XORs the same pattern back.
//   - compute: 20-cyc/step dependent chain, bit-exact vs reference f32 ops.
//   - spikes stored per-lane dwordx4, fire-and-forget.

constexpr float TH     = 0.1f;
constexpr int   T      = 8192;
constexpr int   NCH    = 4096;
constexpr int   CPB    = 16;             // channels per block
constexpr int   NBLK   = NCH / CPB;      // 256 blocks (one per CU)
constexpr int   TILE   = 128;            // timesteps per staged tile
constexpr int   NTILE  = T / TILE;       // 64
constexpr int   NCHUNK = TILE / 4;       // 32 x 16B chunks per row-tile

typedef __attribute__((address_space(1))) const float gfloat;
typedef __attribute__((address_space(3))) float       lfloat;

__device__ __forceinline__ void gload_lds16(const void* g, void* l) {
    __builtin_amdgcn_global_load_lds((const gfloat*)g, (lfloat*)l, 16, 0, 0);
}

// Bit-exact reference step:
//   err = x - recon; net = (err>th)-(err<-th); recon += net*th; spike = net.
// nth in {0,+0.1f,-0.1f} exact; recon update is the same single f32 add as the
// reference; nth*10.0f is exactly {-1.0f,0.0f,1.0f}. No mul feeds an add, so
// FMA contraction cannot change rounding.
__device__ __forceinline__ void dm_step(float xv, float& recon, float& spike) {
    float err = xv - recon;
    float nth = 0.0f;
    nth = (err > TH)  ?  TH : nth;
    nth = (err < -TH) ? -TH : nth;
    recon += nth;
    spike = nth * 10.0f;
}

__global__ __launch_bounds__(64) void dm_scan(const float* __restrict__ x,
                                              float* __restrict__ out) {
    __shared__ float xb[2][CPB][TILE];   // 16 KiB
    const int lane   = threadIdx.x;
    const int chBase = blockIdx.x * CPB;

    // Per-lane global byte offsets for the 8 staging DMAs. Instruction i
    // covers rows 2i (lanes 0-31) and 2i+1 (lanes 32-63); LDS slot s = lane&31
    // of row r must hold data chunk c = s ^ (r&7)  (the swizzle).
    uint32_t voff[8];
#pragma unroll
    for (int i = 0; i < 8; ++i) {
        int r = 2 * i + (lane >> 5);
        int s = lane & 31;
        int c = s ^ (r & 7);
        voff[i] = (uint32_t)r * (uint32_t)(T * 4) + (uint32_t)c * 16u;
    }
    const char* panel = (const char*)(x + (size_t)chBase * T);

    auto stage = [&](int tt, int b) {
        const char* pt = panel + (size_t)tt * (TILE * 4);
#pragma unroll
        for (int i = 0; i < 8; ++i) {
            gload_lds16(pt + voff[i], &xb[b][2 * i][0]);
        }
    };

    stage(0, 0);

    float recon = 0.0f;
    const char* lb = (const char*)&xb[0][0][0];
    // Read-side swizzle base: byte = lane*512 + ((lane&7)<<4); chunk c is read
    // at lb + (blb ^ (c*16)) — same involution the DMA source applied.
    const uint32_t swz = (uint32_t)lane * 512u + (uint32_t)((lane & 7) << 4);
    float4* po = (float4*)(out + (size_t)(chBase + (lane & (CPB - 1))) * T);

    for (int tt = 0; tt < NTILE; ++tt) {
        const int b = tt & 1;
        // Loads for tile tt were issued a full tile ago -> landed; this also
        // drains last tile's stores (counter granularity tax, ~300 cyc).
        asm volatile("s_waitcnt vmcnt(0)" ::: "memory");
        if (tt + 1 < NTILE) stage(tt + 1, b ^ 1);   // async prefetch

        if (lane < CPB) {
            const uint32_t blb = swz + (uint32_t)b * (uint32_t)(CPB * TILE * 4);
#pragma unroll
            for (int c = 0; c < NCHUNK; ++c) {
                float4 xv = *(const float4*)(lb + (blb ^ (uint32_t)(c * 16)));
                float4 s;
                dm_step(xv.x, recon, s.x);
                dm_step(xv.y, recon, s.y);
                dm_step(xv.z, recon, s.z);
                dm_step(xv.w, recon, s.w);
                po[tt * NCHUNK + c] = s;
            }
        }
    }
}

extern "C" void kernel_launch(void* const* d_in, const int* in_sizes, int n_in,
                              void* d_out, int out_size, void* d_ws, size_t ws_size,
                              hipStream_t stream) {
    const float* x   = (const float*)d_in[0];
    float*       out = (float*)d_out;
    dm_scan<<<NBLK, 64, 0, stream>>>(x, out);
}